// Round 19
// baseline (123.840 us; speedup 1.0000x reference)
//
#include <hip/hip_runtime.h>

#define NNODES 50000
#define NEDGES 800000
#define ETOT   (NEDGES + NNODES)
#define FIN    128
#define FOUT   128
#define HEADS  4
#define NEG    0.2f
#define RCAP   64          // fixed CSR row capacity (real edges; P(deg>63) ~ 3e-18/node)
#define WSTR   136         // padded LDS row stride (ushorts)
#define NBUCK  196         // dst>>8 buckets (256 nodes each)
#define NBLK   196         // bin blocks (4096 edges each)
#define SEGC   64          // per-(block,bucket) segment capacity (mean 20.9, ~9 sigma)

typedef float  f32x4 __attribute__((ext_vector_type(4)));
typedef int    i32x4 __attribute__((ext_vector_type(4)));
typedef short  s16x8 __attribute__((ext_vector_type(8)));
typedef unsigned short u16x8 __attribute__((ext_vector_type(8)));

__device__ __forceinline__ float lrelu(float v) { return v > 0.f ? v : NEG * v; }
__device__ __forceinline__ float4 e4(float4 a, float4 b) {
    return make_float4(__expf(lrelu(a.x + b.x)), __expf(lrelu(a.y + b.y)),
                       __expf(lrelu(a.z + b.z)), __expf(lrelu(a.w + b.w)));
}
__device__ __forceinline__ unsigned short f2bf(float f) {   // RNE
    unsigned u = __float_as_uint(f);
    return (unsigned short)((u + 0x7FFFu + ((u >> 16) & 1u)) >> 16);
}
__device__ __forceinline__ void nt_store4(float* p, float a, float b, float c, float d) {
    f32x4 v = {a, b, c, d};
    __builtin_nontemporal_store(v, (f32x4*)p);
}

// ---------------- K1: fused {bin | wt} ----------------
// blocks 0..195: deterministic-segment edge binning (no global atomics, no pre-zeroing).
// block 196: W -> Wt (transposed bf16).
__global__ __launch_bounds__(256) void k_binwt(
    const int* __restrict__ ei, int* __restrict__ cntb, unsigned* __restrict__ region,
    const float* __restrict__ W, unsigned short* __restrict__ Wt)
{
    const int tid = threadIdx.x;

    if (blockIdx.x == NBLK) {
        // ---- wt branch ----
        for (int i = tid; i < 4096; i += 256) {
            const int c = i & 127, kq = i >> 7;
            const int k0 = kq * 4;
            ushort4 v;
            v.x = f2bf(W[(k0 + 0) * 128 + c]);
            v.y = f2bf(W[(k0 + 1) * 128 + c]);
            v.z = f2bf(W[(k0 + 2) * 128 + c]);
            v.w = f2bf(W[(k0 + 3) * 128 + c]);
            *(ushort4*)(Wt + c * 128 + k0) = v;
        }
        return;
    }

    // ---- bin branch ----
    __shared__ int lcnt[256], lofs[256], scan[256], lpos[256];
    __shared__ unsigned recs[4096];              // 16 KiB
    const int blk = blockIdx.x;
    const int q0 = blk * 1024;                   // quad base

    lcnt[tid] = 0;
    __syncthreads();

    i32x4 sq[4], dq[4];
    bool v[4];
#pragma unroll
    for (int j = 0; j < 4; j++) {
        const int q = q0 + tid + j * 256;
        v[j] = (q < NEDGES / 4);
        const int qi = v[j] ? q : 0;
        sq[j] = ((const i32x4*)ei)[qi];
        dq[j] = ((const i32x4*)(ei + NEDGES))[qi];
    }
#pragma unroll
    for (int j = 0; j < 4; j++)
        if (v[j]) {
#pragma unroll
            for (int c = 0; c < 4; c++) atomicAdd(&lcnt[dq[j][c] >> 8], 1);
        }
    __syncthreads();
    scan[tid] = lcnt[tid];
    __syncthreads();
    for (int o = 1; o < 256; o <<= 1) {
        int t = (tid >= o) ? scan[tid - o] : 0;
        __syncthreads();
        scan[tid] += t;
        __syncthreads();
    }
    lofs[tid] = scan[tid] - lcnt[tid];
    if (tid < NBUCK) cntb[blk * NBUCK + tid] = lcnt[tid];   // unconditional each call
    lpos[tid] = 0;
    __syncthreads();
#pragma unroll
    for (int j = 0; j < 4; j++)
        if (v[j]) {
#pragma unroll
            for (int c = 0; c < 4; c++) {
                const int d = dq[j][c], b = d >> 8;
                const int idx = lofs[b] + atomicAdd(&lpos[b], 1);
                recs[idx] = (unsigned)sq[j][c] | ((unsigned)d << 16);
            }
        }
    __syncthreads();
    // linear drain: consecutive i -> contiguous per-(blk,bucket) segments
    const int m = scan[255];
    for (int i = tid; i < m; i += 256) {
        const unsigned rec = recs[i];
        const int b = rec >> 24;
        const int off = i - lofs[b];
        if (off < SEGC)
            region[((size_t)blk * NBUCK + b) * SEGC + off] = rec;
    }
}

// ---------------- K2: assemble CSR rows in LDS from per-block segments ----------------
__global__ __launch_bounds__(256) void k_asm(
    const unsigned* __restrict__ region, const int* __restrict__ cntb,
    int* __restrict__ cnt, unsigned short* __restrict__ csr16)
{
    __shared__ unsigned short rows[256 * RCAP];   // 32 KiB
    __shared__ int lcnt[256];
    const int tid = threadIdx.x;
    const int b = blockIdx.x;
    const int wid = tid >> 6, lane = tid & 63;
    lcnt[tid] = 0;
    __syncthreads();

    for (int blk = wid; blk < NBLK; blk += 4) {
        const int c = min(cntb[blk * NBUCK + b], SEGC);
        const unsigned* seg = region + ((size_t)blk * NBUCK + b) * SEGC;
        for (int i = lane; i < c; i += 64) {
            const unsigned u = seg[i];
            const int dl = (u >> 16) & 255;
            const int sl = atomicAdd(&lcnt[dl], 1);
            if (sl < RCAP) rows[dl * RCAP + sl] = (unsigned short)(u & 0xFFFFu);
        }
    }
    __syncthreads();

    const int nodebase = b * 256;
    const int nrows = min(256, NNODES - nodebase);
    for (int i = tid; i < nrows * 8; i += 256) {
        const int r = i >> 3, q = i & 7;
        *(u16x8*)(&csr16[((size_t)(nodebase + r) << 6) + q * 8]) =
            *(const u16x8*)(&rows[r * RCAP + q * 8]);
    }
    if (tid < nrows) cnt[nodebase + tid] = lcnt[tid];
}

// ---------------- K3: h = x @ W via bf16 MFMA (LDS-staged W), fused a_src/a_dst ------
__global__ __launch_bounds__(256) void k_gemm(
    const float* __restrict__ x, const unsigned short* __restrict__ Wtg,
    const float* __restrict__ att_s, const float* __restrict__ att_d,
    unsigned short* __restrict__ hb, float* __restrict__ a_src, float* __restrict__ a_dst)
{
    __shared__ unsigned short Wl[128 * WSTR];   // 34816 B
    __shared__ unsigned short Xl[64 * WSTR];    // 17408 B

    const int tid = threadIdx.x;
    const int nbase = blockIdx.x * 64;

    for (int i = tid; i < 2048; i += 256) {
        int c = i >> 4, q = i & 15;
        *(u16x8*)(&Wl[c * WSTR + q * 8]) = *(const u16x8*)(&Wtg[c * 128 + q * 8]);
    }
#pragma unroll
    for (int it = 0; it < 8; it++) {
        int flat = it * 256 + tid;
        int row = flat >> 5, kq = flat & 31;
        int gn = nbase + row; if (gn >= NNODES) gn = NNODES - 1;
        float4 v = *(const float4*)(x + (size_t)gn * FIN + kq * 4);
        ushort4 b;
        b.x = f2bf(v.x); b.y = f2bf(v.y); b.z = f2bf(v.z); b.w = f2bf(v.w);
        *(ushort4*)(&Xl[row * WSTR + kq * 4]) = b;
    }
    __syncthreads();

    const int wid = tid >> 6, lane = tid & 63;
    const int r16 = lane & 15;
    const int kg  = lane >> 4;

    s16x8 af[4];
#pragma unroll
    for (int t = 0; t < 4; t++)
        af[t] = *(const s16x8*)(&Xl[(wid * 16 + r16) * WSTR + t * 32 + kg * 8]);

    float pa[4] = {0.f, 0.f, 0.f, 0.f};
    float pd[4] = {0.f, 0.f, 0.f, 0.f};

#pragma unroll
    for (int cg = 0; cg < 8; cg++) {
        s16x8 bf[4];
#pragma unroll
        for (int t = 0; t < 4; t++)
            bf[t] = *(const s16x8*)(&Wl[(cg * 16 + r16) * WSTR + t * 32 + kg * 8]);
        f32x4 acc = {0.f, 0.f, 0.f, 0.f};
#pragma unroll
        for (int t = 0; t < 4; t++)
            acc = __builtin_amdgcn_mfma_f32_16x16x32_bf16(af[t], bf[t], acc, 0, 0, 0);

        const int col = cg * 16 + r16;
        const float asv = att_s[col], adv = att_d[col];
#pragma unroll
        for (int i2 = 0; i2 < 4; i2++) {
            int node = nbase + wid * 16 + kg * 4 + i2;
            if (node < NNODES)
                hb[(size_t)node * FOUT + col] = f2bf(acc[i2]);
            pa[i2] = fmaf(acc[i2], asv, pa[i2]);
            pd[i2] = fmaf(acc[i2], adv, pd[i2]);
        }
        if (cg & 1) {
            const int head = cg >> 1;
#pragma unroll
            for (int i2 = 0; i2 < 4; i2++) {
                float a = pa[i2], d = pd[i2];
                a += __shfl_xor(a, 1); a += __shfl_xor(a, 2);
                a += __shfl_xor(a, 4); a += __shfl_xor(a, 8);
                d += __shfl_xor(d, 1); d += __shfl_xor(d, 2);
                d += __shfl_xor(d, 4); d += __shfl_xor(d, 8);
                if (r16 == 0) {
                    int node = nbase + wid * 16 + kg * 4 + i2;
                    if (node < NNODES) {
                        a_src[node * HEADS + head] = a;
                        a_dst[node * HEADS + head] = d;
                    }
                }
                pa[i2] = 0.f; pd[i2] = 0.f;
            }
        }
    }
}

// ---------------- K4: wave-per-node aggregation, 16 lanes/edge, pipelined --------
__global__ __launch_bounds__(256) void k_msg(
    const unsigned short* __restrict__ hb, const float* __restrict__ a_src,
    const float* __restrict__ a_dst, const int* __restrict__ cnt,
    const unsigned short* __restrict__ csr16, const float* __restrict__ bias,
    float* __restrict__ out, float* __restrict__ nd)
{
    const int tid = threadIdx.x;
    const int wid = tid >> 6, lane = tid & 63;
    const int n = blockIdx.x * 4 + wid;            // 50000 % 4 == 0
    __shared__ unsigned short slds[4][RCAP];       // 512 B
    __shared__ float elds[4][RCAP * 4];            // 4 KiB

    const int deg_r = min(cnt[n], RCAP - 1);       // real in-edges
    const int deg = deg_r + 1;                     // + self loop
    const float4 ad = ((const float4*)a_dst)[n];

    unsigned s = (unsigned)n;                      // self loop src (lane == deg_r)
    float4 ev = make_float4(0.f, 0.f, 0.f, 0.f);
    if (lane < deg) {
        if (lane < deg_r) s = csr16[(n << 6) + lane];
        float4 as = ((const float4*)a_src)[s];
        ev = e4(as, ad);
    }
    float4 den = ev;
#pragma unroll
    for (int o = 32; o >= 1; o >>= 1) {
        den.x += __shfl_xor(den.x, o);
        den.y += __shfl_xor(den.y, o);
        den.z += __shfl_xor(den.z, o);
        den.w += __shfl_xor(den.w, o);
    }
    const float4 inv = make_float4(1.f / (den.x + 1e-16f), 1.f / (den.y + 1e-16f),
                                   1.f / (den.z + 1e-16f), 1.f / (den.w + 1e-16f));
    if (lane == 0) {
        ((float4*)nd)[n * 2]     = ad;
        ((float4*)nd)[n * 2 + 1] = inv;
    }
    slds[wid][lane] = (unsigned short)s;           // beyond deg: elds=0 makes it harmless
    ((float4*)elds[wid])[lane] =
        make_float4(ev.x * inv.x, ev.y * inv.y, ev.z * inv.z, ev.w * inv.w);
    // wave-internal LDS: same lockstep wave -> no barrier

    // Phase B: 16 lanes/edge, 4 edge-groups, 2-stage pipeline (8 gathers in flight/wave)
    const int sub = lane >> 4;
    const int c8  = lane & 15;
    const int head = c8 >> 2;
    const char* hbase = (const char*)hb;
    float acc[8];
#pragma unroll
    for (int j = 0; j < 8; j++) acc[j] = 0.f;
    const int dp = (deg + 3) & ~3;                 // >= 4 always

    float al = elds[wid][sub * 4 + head];
    unsigned si = slds[wid][sub];
    float4 u = *(const float4*)(hbase + si * 256u + c8 * 16u);

    for (int base = 4; base < dp; base += 4) {
        const int i1 = base + sub;
        const float al2 = elds[wid][i1 * 4 + head];
        const unsigned si2 = slds[wid][i1];
        const float4 u2 = *(const float4*)(hbase + si2 * 256u + c8 * 16u);

        const unsigned w0 = __float_as_uint(u.x), w1 = __float_as_uint(u.y);
        const unsigned w2 = __float_as_uint(u.z), w3 = __float_as_uint(u.w);
        acc[0] = fmaf(__uint_as_float(w0 << 16),          al, acc[0]);
        acc[1] = fmaf(__uint_as_float(w0 & 0xFFFF0000u),  al, acc[1]);
        acc[2] = fmaf(__uint_as_float(w1 << 16),          al, acc[2]);
        acc[3] = fmaf(__uint_as_float(w1 & 0xFFFF0000u),  al, acc[3]);
        acc[4] = fmaf(__uint_as_float(w2 << 16),          al, acc[4]);
        acc[5] = fmaf(__uint_as_float(w2 & 0xFFFF0000u),  al, acc[5]);
        acc[6] = fmaf(__uint_as_float(w3 << 16),          al, acc[6]);
        acc[7] = fmaf(__uint_as_float(w3 & 0xFFFF0000u),  al, acc[7]);

        u = u2; al = al2;
    }
    {
        const unsigned w0 = __float_as_uint(u.x), w1 = __float_as_uint(u.y);
        const unsigned w2 = __float_as_uint(u.z), w3 = __float_as_uint(u.w);
        acc[0] = fmaf(__uint_as_float(w0 << 16),          al, acc[0]);
        acc[1] = fmaf(__uint_as_float(w0 & 0xFFFF0000u),  al, acc[1]);
        acc[2] = fmaf(__uint_as_float(w1 << 16),          al, acc[2]);
        acc[3] = fmaf(__uint_as_float(w1 & 0xFFFF0000u),  al, acc[3]);
        acc[4] = fmaf(__uint_as_float(w2 << 16),          al, acc[4]);
        acc[5] = fmaf(__uint_as_float(w2 & 0xFFFF0000u),  al, acc[5]);
        acc[6] = fmaf(__uint_as_float(w3 << 16),          al, acc[6]);
        acc[7] = fmaf(__uint_as_float(w3 & 0xFFFF0000u),  al, acc[7]);
    }
#pragma unroll
    for (int j = 0; j < 8; j++) {
        acc[j] += __shfl_xor(acc[j], 16);
        acc[j] += __shfl_xor(acc[j], 32);
    }
    if (lane < 16) {
        const float4 b0 = ((const float4*)bias)[c8 * 2];
        const float4 b1 = ((const float4*)bias)[c8 * 2 + 1];
        ((float4*)out)[(size_t)n * 32 + c8 * 2] =
            make_float4(acc[0] + b0.x, acc[1] + b0.y, acc[2] + b0.z, acc[3] + b0.w);
        ((float4*)out)[(size_t)n * 32 + c8 * 2 + 1] =
            make_float4(acc[4] + b1.x, acc[5] + b1.y, acc[6] + b1.z, acc[7] + b1.w);
    }
}

// ---------------- K5: alpha + edge_index_full, quad-per-thread, eid order ----------------
__global__ __launch_bounds__(256) void k_alpha(
    const int* __restrict__ ei, const float* __restrict__ a_src,
    const float* __restrict__ nd, float* __restrict__ alpha,
    float* __restrict__ out_edge)
{
    const int i4 = blockIdx.x * blockDim.x + threadIdx.x;
    if (i4 >= ETOT / 4) return;
    i32x4 s4, d4;
    if (i4 < NEDGES / 4) {
        s4 = __builtin_nontemporal_load(&((const i32x4*)ei)[i4]);
        d4 = __builtin_nontemporal_load(&((const i32x4*)ei)[NEDGES / 4 + i4]);
    } else {
        const int n0 = i4 * 4 - NEDGES;
        s4 = d4 = (i32x4){n0, n0 + 1, n0 + 2, n0 + 3};
    }
    nt_store4(out_edge + (size_t)i4 * 4,
              (float)s4.x, (float)s4.y, (float)s4.z, (float)s4.w);
    nt_store4(out_edge + (size_t)(ETOT / 4 + i4) * 4,
              (float)d4.x, (float)d4.y, (float)d4.z, (float)d4.w);

    const float4* as4p = (const float4*)a_src;
    const float4* nd4p = (const float4*)nd;
#pragma unroll
    for (int j = 0; j < 4; j++) {
        const int s = s4[j];
        const int d = d4[j];
        float4 as = as4p[s];
        float4 ad = nd4p[d * 2];
        float4 iv = nd4p[d * 2 + 1];
        float4 ev = e4(as, ad);
        nt_store4(alpha + ((size_t)i4 * 4 + j) * 4,
                  ev.x * iv.x, ev.y * iv.y, ev.z * iv.z, ev.w * iv.w);
    }
}

// ---------------- launcher ----------------
extern "C" void kernel_launch(void* const* d_in, const int* in_sizes, int n_in,
                              void* d_out, int out_size, void* d_ws, size_t ws_size,
                              hipStream_t stream)
{
    const float* x     = (const float*)d_in[0];
    const int*   ei    = (const int*)  d_in[1];
    const float* W     = (const float*)d_in[2];
    const float* att_s = (const float*)d_in[3];
    const float* att_d = (const float*)d_in[4];
    const float* bias  = (const float*)d_in[5];

    unsigned short* hb = (unsigned short*)d_ws;            // 6,400,000 ush (12.8 MB)
    float* a_src  = (float*)(hb + (size_t)NNODES * FOUT);  // 200,000 f
    float* a_dst  = a_src + NNODES * HEADS;                // 200,000 f
    float* nd     = a_dst + NNODES * HEADS;                // 400,000 f {ad4, inv4}
    int*   cnt    = (int*)(nd + (size_t)NNODES * 8);       // 50,000 i
    unsigned short* csr16 = (unsigned short*)(cnt + NNODES); // 3,200,000 ush (6.4 MB)
    unsigned short* wt    = csr16 + (size_t)NNODES * RCAP;   // 16,384 ush (32 KB)
    int*      cntb   = (int*)(wt + 16384);                   // 38,416 i (150 KB)
    unsigned* region = (unsigned*)(cntb + ((NBLK * NBUCK + 15) & ~15)); // 2,458,624 u (9.8 MB)

    float* out_x = (float*)d_out;
    float* out_e = out_x + (size_t)NNODES * FOUT;
    float* out_a = out_e + (size_t)2 * ETOT;

    k_binwt<<<NBLK + 1, 256, 0, stream>>>(ei, cntb, region, W, wt);
    k_asm  <<<NBUCK, 256, 0, stream>>>(region, cntb, cnt, csr16);
    k_gemm <<<(NNODES + 63) / 64, 256, 0, stream>>>(x, wt, att_s, att_d, hb, a_src, a_dst);
    k_msg  <<<NNODES / 4, 256, 0, stream>>>(hb, a_src, a_dst, cnt, csr16, bias, out_x, nd);
    k_alpha<<<(ETOT / 4 + 255) / 256, 256, 0, stream>>>(ei, a_src, nd, out_a, out_e);
}

// Round 20
// 104.058 us; speedup vs baseline: 1.1901x; 1.1901x over previous
//
#include <hip/hip_runtime.h>

#define NNODES 50000
#define NEDGES 800000
#define ETOT   (NEDGES + NNODES)
#define FIN    128
#define FOUT   128
#define HEADS  4
#define NEG    0.2f
#define RCAP   64          // fixed CSR row capacity (real edges; P(deg>63) ~ 3e-18/node)
#define WSTR   136         // padded LDS row stride (ushorts)
#define NBUCK  196         // dst>>8 buckets (256 nodes each)
#define CAPB   4608        // per-bucket region capacity (mean 4096, +8 sigma)

typedef float  f32x4 __attribute__((ext_vector_type(4)));
typedef int    i32x4 __attribute__((ext_vector_type(4)));
typedef short  s16x8 __attribute__((ext_vector_type(8)));
typedef unsigned short u16x8 __attribute__((ext_vector_type(8)));

__device__ __forceinline__ float lrelu(float v) { return v > 0.f ? v : NEG * v; }
__device__ __forceinline__ float4 e4(float4 a, float4 b) {
    return make_float4(__expf(lrelu(a.x + b.x)), __expf(lrelu(a.y + b.y)),
                       __expf(lrelu(a.z + b.z)), __expf(lrelu(a.w + b.w)));
}
__device__ __forceinline__ unsigned short f2bf(float f) {   // RNE
    unsigned u = __float_as_uint(f);
    return (unsigned short)((u + 0x7FFFu + ((u >> 16) & 1u)) >> 16);
}
__device__ __forceinline__ void nt_store4(float* p, float a, float b, float c, float d) {
    f32x4 v = {a, b, c, d};
    __builtin_nontemporal_store(v, (f32x4*)p);
}

// ---------------- K0: W -> Wt (transposed, bf16); also zeros gcnt ----------------
__global__ __launch_bounds__(256) void k_wt(const float* __restrict__ W,
                                            unsigned short* __restrict__ Wt,
                                            int* __restrict__ gcnt)
{
    if (blockIdx.x == 0 && threadIdx.x < NBUCK) gcnt[threadIdx.x] = 0;
    const int i = blockIdx.x * 256 + threadIdx.x;   // 4096 = 128c x 32kq
    const int c = i & 127, kq = i >> 7;
    const int k0 = kq * 4;
    ushort4 v;
    v.x = f2bf(W[(k0 + 0) * 128 + c]);
    v.y = f2bf(W[(k0 + 1) * 128 + c]);
    v.z = f2bf(W[(k0 + 2) * 128 + c]);
    v.w = f2bf(W[(k0 + 3) * 128 + c]);
    *(ushort4*)(Wt + c * 128 + k0) = v;
}

// ---------------- K1: h = x @ W via bf16 MFMA, fused a_src/a_dst ----------------
__global__ __launch_bounds__(256) void k_gemm(
    const float* __restrict__ x, const unsigned short* __restrict__ Wtg,
    const float* __restrict__ att_s, const float* __restrict__ att_d,
    unsigned short* __restrict__ hb, float* __restrict__ a_src, float* __restrict__ a_dst)
{
    __shared__ unsigned short Wl[128 * WSTR];   // 34816 B
    __shared__ unsigned short Xl[64 * WSTR];    // 17408 B

    const int tid = threadIdx.x;
    const int nbase = blockIdx.x * 64;

    for (int i = tid; i < 2048; i += 256) {
        int c = i >> 4, q = i & 15;
        *(u16x8*)(&Wl[c * WSTR + q * 8]) = *(const u16x8*)(&Wtg[c * 128 + q * 8]);
    }
#pragma unroll
    for (int it = 0; it < 8; it++) {
        int flat = it * 256 + tid;
        int row = flat >> 5, kq = flat & 31;
        int gn = nbase + row; if (gn >= NNODES) gn = NNODES - 1;
        float4 v = *(const float4*)(x + (size_t)gn * FIN + kq * 4);
        ushort4 b;
        b.x = f2bf(v.x); b.y = f2bf(v.y); b.z = f2bf(v.z); b.w = f2bf(v.w);
        *(ushort4*)(&Xl[row * WSTR + kq * 4]) = b;
    }
    __syncthreads();

    const int wid = tid >> 6, lane = tid & 63;
    const int r16 = lane & 15;
    const int kg  = lane >> 4;

    s16x8 af[4];
#pragma unroll
    for (int t = 0; t < 4; t++)
        af[t] = *(const s16x8*)(&Xl[(wid * 16 + r16) * WSTR + t * 32 + kg * 8]);

    float pa[4] = {0.f, 0.f, 0.f, 0.f};
    float pd[4] = {0.f, 0.f, 0.f, 0.f};

#pragma unroll
    for (int cg = 0; cg < 8; cg++) {
        s16x8 bf[4];
#pragma unroll
        for (int t = 0; t < 4; t++)
            bf[t] = *(const s16x8*)(&Wl[(cg * 16 + r16) * WSTR + t * 32 + kg * 8]);
        f32x4 acc = {0.f, 0.f, 0.f, 0.f};
#pragma unroll
        for (int t = 0; t < 4; t++)
            acc = __builtin_amdgcn_mfma_f32_16x16x32_bf16(af[t], bf[t], acc, 0, 0, 0);

        const int col = cg * 16 + r16;
        const float asv = att_s[col], adv = att_d[col];
#pragma unroll
        for (int i2 = 0; i2 < 4; i2++) {
            int node = nbase + wid * 16 + kg * 4 + i2;
            if (node < NNODES)
                hb[(size_t)node * FOUT + col] = f2bf(acc[i2]);
            pa[i2] = fmaf(acc[i2], asv, pa[i2]);
            pd[i2] = fmaf(acc[i2], adv, pd[i2]);
        }
        if (cg & 1) {
            const int head = cg >> 1;
#pragma unroll
            for (int i2 = 0; i2 < 4; i2++) {
                float a = pa[i2], d = pd[i2];
                a += __shfl_xor(a, 1); a += __shfl_xor(a, 2);
                a += __shfl_xor(a, 4); a += __shfl_xor(a, 8);
                d += __shfl_xor(d, 1); d += __shfl_xor(d, 2);
                d += __shfl_xor(d, 4); d += __shfl_xor(d, 8);
                if (r16 == 0) {
                    int node = nbase + wid * 16 + kg * 4 + i2;
                    if (node < NNODES) {
                        a_src[node * HEADS + head] = a;
                        a_dst[node * HEADS + head] = d;
                    }
                }
                pa[i2] = 0.f; pd[i2] = 0.f;
            }
        }
    }
}

// ---------------- K2a: bin edges by dst>>8; LDS-ordered records, coalesced drain ----
__global__ __launch_bounds__(256) void k_bin(
    const int* __restrict__ ei, int* __restrict__ gcnt, unsigned* __restrict__ region)
{
    __shared__ int lcnt[256], lofs[256], gbase[256], lpos[256], scan[256];
    __shared__ unsigned recs[4096];              // 16 KiB
    const int tid = threadIdx.x;
    const int q0 = blockIdx.x * 1024;            // quad base

    lcnt[tid] = 0;
    __syncthreads();

    i32x4 sq[4], dq[4];
    bool v[4];
#pragma unroll
    for (int j = 0; j < 4; j++) {
        const int q = q0 + tid + j * 256;
        v[j] = (q < NEDGES / 4);
        const int qi = v[j] ? q : 0;
        sq[j] = ((const i32x4*)ei)[qi];
        dq[j] = ((const i32x4*)(ei + NEDGES))[qi];
    }
#pragma unroll
    for (int j = 0; j < 4; j++)
        if (v[j]) {
#pragma unroll
            for (int c = 0; c < 4; c++) atomicAdd(&lcnt[dq[j][c] >> 8], 1);
        }
    __syncthreads();
    scan[tid] = lcnt[tid];
    __syncthreads();
    for (int o = 1; o < 256; o <<= 1) {
        int t = (tid >= o) ? scan[tid - o] : 0;
        __syncthreads();
        scan[tid] += t;
        __syncthreads();
    }
    lofs[tid] = scan[tid] - lcnt[tid];
    if (tid < NBUCK) gbase[tid] = atomicAdd(&gcnt[tid], lcnt[tid]);
    lpos[tid] = 0;
    __syncthreads();
#pragma unroll
    for (int j = 0; j < 4; j++)
        if (v[j]) {
#pragma unroll
            for (int c = 0; c < 4; c++) {
                const int d = dq[j][c], b = d >> 8;
                const int idx = lofs[b] + atomicAdd(&lpos[b], 1);
                recs[idx] = (unsigned)sq[j][c] | ((unsigned)d << 16);
            }
        }
    __syncthreads();
    const int m = scan[255];
    for (int i = tid; i < m; i += 256) {
        const unsigned rec = recs[i];
        const int b = rec >> 24;
        const int off = gbase[b] + (i - lofs[b]);
        if (off < CAPB) region[(size_t)b * CAPB + off] = rec;
    }
}

// ---------------- K2b: assemble CSR rows in LDS, bulk write ----------------
__global__ __launch_bounds__(256) void k_asm(
    const unsigned* __restrict__ region, const int* __restrict__ gcnt,
    int* __restrict__ cnt, unsigned short* __restrict__ csr16)
{
    __shared__ unsigned short rows[256 * RCAP];   // 32 KiB
    __shared__ int lcnt[256];
    const int tid = threadIdx.x;
    const int b = blockIdx.x;
    lcnt[tid] = 0;
    __syncthreads();

    const int m = min(gcnt[b], CAPB);
    for (int i = tid; i < m; i += 256) {
        const unsigned u = region[(size_t)b * CAPB + i];
        const int dl = (u >> 16) & 255;
        const int sl = atomicAdd(&lcnt[dl], 1);
        if (sl < RCAP) rows[dl * RCAP + sl] = (unsigned short)(u & 0xFFFFu);
    }
    __syncthreads();

    const int nodebase = b * 256;
    const int nrows = min(256, NNODES - nodebase);
    for (int i = tid; i < nrows * 8; i += 256) {
        const int r = i >> 3, q = i & 7;
        *(u16x8*)(&csr16[((size_t)(nodebase + r) << 6) + q * 8]) =
            *(const u16x8*)(&rows[r * RCAP + q * 8]);
    }
    if (tid < nrows) cnt[nodebase + tid] = lcnt[tid];
}

// ---------------- K3: wave-per-node aggregation, 16 lanes/edge, pipelined --------
__global__ __launch_bounds__(256) void k_msg(
    const unsigned short* __restrict__ hb, const float* __restrict__ a_src,
    const float* __restrict__ a_dst, const int* __restrict__ cnt,
    const unsigned short* __restrict__ csr16, const float* __restrict__ bias,
    float* __restrict__ out, float* __restrict__ nd)
{
    const int tid = threadIdx.x;
    const int wid = tid >> 6, lane = tid & 63;
    const int n = blockIdx.x * 4 + wid;            // 50000 % 4 == 0
    __shared__ unsigned short slds[4][RCAP];       // 512 B
    __shared__ float elds[4][RCAP * 4];            // 4 KiB

    const int deg_r = min(cnt[n], RCAP - 1);       // real in-edges
    const int deg = deg_r + 1;                     // + self loop
    const float4 ad = ((const float4*)a_dst)[n];

    unsigned s = (unsigned)n;                      // self loop src (lane == deg_r)
    float4 ev = make_float4(0.f, 0.f, 0.f, 0.f);
    if (lane < deg) {
        if (lane < deg_r) s = csr16[(n << 6) + lane];
        float4 as = ((const float4*)a_src)[s];
        ev = e4(as, ad);
    }
    float4 den = ev;
#pragma unroll
    for (int o = 32; o >= 1; o >>= 1) {
        den.x += __shfl_xor(den.x, o);
        den.y += __shfl_xor(den.y, o);
        den.z += __shfl_xor(den.z, o);
        den.w += __shfl_xor(den.w, o);
    }
    const float4 inv = make_float4(1.f / (den.x + 1e-16f), 1.f / (den.y + 1e-16f),
                                   1.f / (den.z + 1e-16f), 1.f / (den.w + 1e-16f));
    if (lane == 0) {
        ((float4*)nd)[n * 2]     = ad;
        ((float4*)nd)[n * 2 + 1] = inv;
    }
    slds[wid][lane] = (unsigned short)s;           // beyond deg: elds=0 makes it harmless
    ((float4*)elds[wid])[lane] =
        make_float4(ev.x * inv.x, ev.y * inv.y, ev.z * inv.z, ev.w * inv.w);
    // wave-internal LDS: same lockstep wave -> no barrier

    // Phase B: 16 lanes/edge, 4 edge-groups, 2-stage pipeline (8 gathers in flight/wave)
    const int sub = lane >> 4;
    const int c8  = lane & 15;
    const int head = c8 >> 2;
    const char* hbase = (const char*)hb;
    float acc[8];
#pragma unroll
    for (int j = 0; j < 8; j++) acc[j] = 0.f;
    const int dp = (deg + 3) & ~3;                 // >= 4 always

    float al = elds[wid][sub * 4 + head];
    unsigned si = slds[wid][sub];
    float4 u = *(const float4*)(hbase + si * 256u + c8 * 16u);

    for (int base = 4; base < dp; base += 4) {
        const int i1 = base + sub;
        const float al2 = elds[wid][i1 * 4 + head];
        const unsigned si2 = slds[wid][i1];
        const float4 u2 = *(const float4*)(hbase + si2 * 256u + c8 * 16u);

        const unsigned w0 = __float_as_uint(u.x), w1 = __float_as_uint(u.y);
        const unsigned w2 = __float_as_uint(u.z), w3 = __float_as_uint(u.w);
        acc[0] = fmaf(__uint_as_float(w0 << 16),          al, acc[0]);
        acc[1] = fmaf(__uint_as_float(w0 & 0xFFFF0000u),  al, acc[1]);
        acc[2] = fmaf(__uint_as_float(w1 << 16),          al, acc[2]);
        acc[3] = fmaf(__uint_as_float(w1 & 0xFFFF0000u),  al, acc[3]);
        acc[4] = fmaf(__uint_as_float(w2 << 16),          al, acc[4]);
        acc[5] = fmaf(__uint_as_float(w2 & 0xFFFF0000u),  al, acc[5]);
        acc[6] = fmaf(__uint_as_float(w3 << 16),          al, acc[6]);
        acc[7] = fmaf(__uint_as_float(w3 & 0xFFFF0000u),  al, acc[7]);

        u = u2; al = al2;
    }
    {
        const unsigned w0 = __float_as_uint(u.x), w1 = __float_as_uint(u.y);
        const unsigned w2 = __float_as_uint(u.z), w3 = __float_as_uint(u.w);
        acc[0] = fmaf(__uint_as_float(w0 << 16),          al, acc[0]);
        acc[1] = fmaf(__uint_as_float(w0 & 0xFFFF0000u),  al, acc[1]);
        acc[2] = fmaf(__uint_as_float(w1 << 16),          al, acc[2]);
        acc[3] = fmaf(__uint_as_float(w1 & 0xFFFF0000u),  al, acc[3]);
        acc[4] = fmaf(__uint_as_float(w2 << 16),          al, acc[4]);
        acc[5] = fmaf(__uint_as_float(w2 & 0xFFFF0000u),  al, acc[5]);
        acc[6] = fmaf(__uint_as_float(w3 << 16),          al, acc[6]);
        acc[7] = fmaf(__uint_as_float(w3 & 0xFFFF0000u),  al, acc[7]);
    }
#pragma unroll
    for (int j = 0; j < 8; j++) {
        acc[j] += __shfl_xor(acc[j], 16);
        acc[j] += __shfl_xor(acc[j], 32);
    }
    if (lane < 16) {
        const float4 b0 = ((const float4*)bias)[c8 * 2];
        const float4 b1 = ((const float4*)bias)[c8 * 2 + 1];
        ((float4*)out)[(size_t)n * 32 + c8 * 2] =
            make_float4(acc[0] + b0.x, acc[1] + b0.y, acc[2] + b0.z, acc[3] + b0.w);
        ((float4*)out)[(size_t)n * 32 + c8 * 2 + 1] =
            make_float4(acc[4] + b1.x, acc[5] + b1.y, acc[6] + b1.z, acc[7] + b1.w);
    }
}

// ---------------- K4: alpha + edge_index_full, quad-per-thread, eid order ----------------
__global__ __launch_bounds__(256) void k_alpha(
    const int* __restrict__ ei, const float* __restrict__ a_src,
    const float* __restrict__ nd, float* __restrict__ alpha,
    float* __restrict__ out_edge)
{
    const int i4 = blockIdx.x * blockDim.x + threadIdx.x;
    if (i4 >= ETOT / 4) return;
    i32x4 s4, d4;
    if (i4 < NEDGES / 4) {
        s4 = __builtin_nontemporal_load(&((const i32x4*)ei)[i4]);
        d4 = __builtin_nontemporal_load(&((const i32x4*)ei)[NEDGES / 4 + i4]);
    } else {
        const int n0 = i4 * 4 - NEDGES;
        s4 = d4 = (i32x4){n0, n0 + 1, n0 + 2, n0 + 3};
    }
    nt_store4(out_edge + (size_t)i4 * 4,
              (float)s4.x, (float)s4.y, (float)s4.z, (float)s4.w);
    nt_store4(out_edge + (size_t)(ETOT / 4 + i4) * 4,
              (float)d4.x, (float)d4.y, (float)d4.z, (float)d4.w);

    const float4* as4p = (const float4*)a_src;
    const float4* nd4p = (const float4*)nd;
#pragma unroll
    for (int j = 0; j < 4; j++) {
        const int s = s4[j];
        const int d = d4[j];
        float4 as = as4p[s];
        float4 ad = nd4p[d * 2];
        float4 iv = nd4p[d * 2 + 1];
        float4 ev = e4(as, ad);
        nt_store4(alpha + ((size_t)i4 * 4 + j) * 4,
                  ev.x * iv.x, ev.y * iv.y, ev.z * iv.z, ev.w * iv.w);
    }
}

// ---------------- launcher ----------------
extern "C" void kernel_launch(void* const* d_in, const int* in_sizes, int n_in,
                              void* d_out, int out_size, void* d_ws, size_t ws_size,
                              hipStream_t stream)
{
    const float* x     = (const float*)d_in[0];
    const int*   ei    = (const int*)  d_in[1];
    const float* W     = (const float*)d_in[2];
    const float* att_s = (const float*)d_in[3];
    const float* att_d = (const float*)d_in[4];
    const float* bias  = (const float*)d_in[5];

    unsigned short* hb = (unsigned short*)d_ws;            // 6.4M ushort (12.8 MB)
    float* a_src  = (float*)(hb + (size_t)NNODES * FOUT);  // 200,000 f
    float* a_dst  = a_src + NNODES * HEADS;                // 200,000 f
    float* nd     = a_dst + NNODES * HEADS;                // 400,000 f {ad4, inv4}
    int*   cnt    = (int*)(nd + (size_t)NNODES * 8);       // 50,000 i
    unsigned short* csr16 = (unsigned short*)(cnt + NNODES); // 50,000*64 ushort (6.4 MB)
    unsigned short* wt    = csr16 + (size_t)NNODES * RCAP;   // 16,384 ushort (32 KB)
    int*      gcnt  = (int*)(wt + 16384);                    // 196 (+pad) ints
    unsigned* region = (unsigned*)(gcnt + 256);              // 196*4608 uints (3.6 MB)

    float* out_x = (float*)d_out;
    float* out_e = out_x + (size_t)NNODES * FOUT;
    float* out_a = out_e + (size_t)2 * ETOT;

    k_wt   <<<16, 256, 0, stream>>>(W, wt, gcnt);
    k_gemm <<<(NNODES + 63) / 64, 256, 0, stream>>>(x, wt, att_s, att_d, hb, a_src, a_dst);
    k_bin  <<<(NEDGES / 4 + 1023) / 1024, 256, 0, stream>>>(ei, gcnt, region);
    k_asm  <<<NBUCK, 256, 0, stream>>>(region, gcnt, cnt, csr16);
    k_msg  <<<NNODES / 4, 256, 0, stream>>>(hb, a_src, a_dst, cnt, csr16, bias, out_x, nd);
    k_alpha<<<(ETOT / 4 + 255) / 256, 256, 0, stream>>>(ei, a_src, nd, out_a, out_e);
}